// Round 5
// baseline (4937.725 us; speedup 1.0000x reference)
//
#include <hip/hip_runtime.h>
#include <stdint.h>

// Persistent-LSTM, round 4: agent-scope (sc1/IF$) h exchange, non-speculative.
//  - 256 WGs x 128 threads (2 waves). WG (g = bid>>6, m = bid&63) owns
//    batch rows 16g..16g+15 and u-columns 8m..8m+7 (32 z-cols, 2 nt tiles).
//  - One recurrence stream per WG; no cross-WG barriers, no flags.
//  - h element = u32 ((t+1)<<16 | bf16(h)) in parity double buffer.
//    Exchange uses AGENT scope (sc1): bypasses L1 + per-XCD L2, served at
//    the IF$ coherence point (~400 cy) -- NOT system scope (sc0 sc1), which
//    bypasses IF$ and round-trips HBM (round-2 mistake, 1.4 GB FETCH), and
//    NOT sc0-only, which can hit stale near caches (round-3 deadlock).
//  - Poll loop validates embedded tags only (small retry quantum); the
//    repack + MFMA block runs once after validation.
//  - 2-buffer safety: a tag-(t+2) write requires full h_{t+1}, which requires
//    every WG to have finished (and thus consumed) step t -> no WAR race.
//  - Weights staged once to LDS in MFMA B-frag order (48 KB); x-part weight
//    frags preloaded to VGPRs. Waves split K by parity; partial z reduced
//    through a small LDS zbuf with 2 intra-WG barriers per step.

#define Tt   1024
#define Uu   512
#define G4U  2048
#define NWG  256
#define NTHR 128

#define WF_ELEMS (2 * 24 * 64 * 8)                 // 24576 bf16 = 48 KB
#define WF_BYTES (WF_ELEMS * 2)
#define ZB_PLANE (16 * 17)                         // padded 16x16 f32 tile
#define SMEM_BYTES (WF_BYTES + 4 * ZB_PLANE * 4)   // 48 KB + 4352 B

typedef short  bf16x8 __attribute__((ext_vector_type(8)));
typedef float  f32x4  __attribute__((ext_vector_type(4)));
typedef int    int4v  __attribute__((ext_vector_type(4)));
typedef unsigned int u32;

__device__ __forceinline__ unsigned short f2bf(float f) {
  u32 u = __builtin_bit_cast(u32, f);
  u += 0x7fffu + ((u >> 16) & 1u);                 // RNE (finite inputs)
  return (unsigned short)(u >> 16);
}
__device__ __forceinline__ u32 umin32(u32 a, u32 b) { return a < b ? a : b; }

// Agent scope: bypass L1 and the non-coherent per-XCD L2; serve at IF$.
__device__ __forceinline__ int4v load16_ag(const u32* p) {
  int4v r;
  asm volatile("global_load_dwordx4 %0, %1, off sc1"
               : "=v"(r) : "v"(p) : "memory");
  return r;
}
__device__ __forceinline__ void store4_ag(u32* p, u32 v) {
  asm volatile("global_store_dword %0, %1, off sc1"
               :: "v"(p), "v"(v) : "memory");
}

__device__ __forceinline__ float sigf(float z) {
  return __builtin_amdgcn_rcpf(1.f + __expf(-z));
}
__device__ __forceinline__ float tanh_fast(float v) {
  const float e = __expf(-2.f * fabsf(v));
  const float r = (1.f - e) * __builtin_amdgcn_rcpf(1.f + e);
  return copysignf(r, v);
}

extern "C" __global__ void __launch_bounds__(NTHR, 1)
lstm_persistent(const float* __restrict__ x,
                const float* __restrict__ Wk,
                const float* __restrict__ Rk,
                const float* __restrict__ bias,
                float* __restrict__ out,
                u32* __restrict__ hbuf)            // [2][64][512] tagged u32
{
  extern __shared__ char smem[];
  unsigned short* wf   = (unsigned short*)smem;            // [nt][kt][lane][8]
  float*          zbuf = (float*)(smem + WF_BYTES);        // [w][nt][16][17]

  const int bid = blockIdx.x;
  const int tid = threadIdx.x;
  const int w   = tid >> 6;
  const int l   = tid & 63;
  const int g   = bid >> 6;        // row group: batch rows 16g..16g+15
  const int m   = bid & 63;        // u-cols 8m..8m+7

  // ---- one-time weight staging into MFMA B-fragment order ----
  for (int i = tid; i < WF_ELEMS; i += NTHR) {
    const int j    = i & 7;
    const int lane = (i >> 3) & 63;
    const int kt   = (i >> 9) % 24;
    const int nt   = (i >> 9) / 24;
    const int k    = kt * 32 + ((lane >> 4) << 3) + j;     // 0..767
    const int n    = nt * 16 + (lane & 15);                // 0..31
    const int zc   = (n >> 3) * Uu + m * 8 + (n & 7);      // gate*512 + u
    const float v  = (k < 256) ? Wk[(size_t)k * G4U + zc]
                               : Rk[(size_t)(k - 256) * G4U + zc];
    wf[i] = f2bf(v);
  }
  __syncthreads();

  // ---- preload x-part weight fragments (kt = 2q+w, q=0..3) ----
  bf16x8 wfx[4][2];
  #pragma unroll
  for (int q = 0; q < 4; ++q)
    #pragma unroll
    for (int nt = 0; nt < 2; ++nt)
      wfx[q][nt] = *(const bf16x8*)(wf + (((nt * 24) + (2 * q + w)) * 64 + l) * 8);

  // ---- combine-role constants (one (row,u) pair per thread) ----
  const int row_c = tid >> 3;                  // 0..15
  const int uu    = tid & 7;
  const int b_out = g * 16 + row_c;
  const int u_out = m * 8 + uu;
  float breg[4];
  #pragma unroll
  for (int gg = 0; gg < 4; ++gg) breg[gg] = bias[gg * Uu + u_out];
  float creg = 0.f;

  // ---- load-role constants (lane-level, MFMA A-fragment) ----
  const int b_ld = g * 16 + (l & 15);
  const int kq   = (l >> 4) * 8;

  for (int t = 0; t < Tt; ++t) {
    // ---- issue agent-scope tagged-h loads first (latency hides under x) ----
    const u32* hp = hbuf + ((size_t)(t & 1) * 64 + b_ld) * Uu + kq;
    int4v hf[16];
    #pragma unroll
    for (int q = 0; q < 8; ++q) {
      hf[2 * q]     = load16_ag(hp + (2 * q + w) * 32);
      hf[2 * q + 1] = load16_ag(hp + (2 * q + w) * 32 + 4);
    }

    // ---- x phase: fp32 loads + cvt + 8 MFMAs (kt = 2q+w) ----
    f32x4 aX0 = {0.f, 0.f, 0.f, 0.f};
    f32x4 aX1 = {0.f, 0.f, 0.f, 0.f};
    const float* xp = x + ((size_t)b_ld * Tt + t) * 256 + kq;
    #pragma unroll
    for (int q = 0; q < 4; ++q) {
      const int kt = 2 * q + w;
      const float4 v0 = *(const float4*)(xp + kt * 32);
      const float4 v1 = *(const float4*)(xp + kt * 32 + 4);
      int r0, r1, r2, r3;
      asm("v_cvt_pk_bf16_f32 %0, %1, %2" : "=v"(r0) : "v"(v0.x), "v"(v0.y));
      asm("v_cvt_pk_bf16_f32 %0, %1, %2" : "=v"(r1) : "v"(v0.z), "v"(v0.w));
      asm("v_cvt_pk_bf16_f32 %0, %1, %2" : "=v"(r2) : "v"(v1.x), "v"(v1.y));
      asm("v_cvt_pk_bf16_f32 %0, %1, %2" : "=v"(r3) : "v"(v1.z), "v"(v1.w));
      const int4v ai = {r0, r1, r2, r3};
      const bf16x8 a = __builtin_bit_cast(bf16x8, ai);
      aX0 = __builtin_amdgcn_mfma_f32_16x16x32_bf16(a, wfx[q][0], aX0, 0, 0, 0);
      aX1 = __builtin_amdgcn_mfma_f32_16x16x32_bf16(a, wfx[q][1], aX1, 0, 0, 0);
    }

    // ---- h poll: validate embedded tags only (small retry quantum) ----
    for (;;) {
      asm volatile("s_waitcnt vmcnt(0)" ::: "memory");
      __builtin_amdgcn_sched_barrier(0);
      u32 m0 = ~0u, m1 = ~0u, m2 = ~0u, m3 = ~0u;
      #pragma unroll
      for (int q = 0; q < 16; ++q) {
        m0 = umin32(m0, (u32)hf[q][0]);
        m1 = umin32(m1, (u32)hf[q][1]);
        m2 = umin32(m2, (u32)hf[q][2]);
        m3 = umin32(m3, (u32)hf[q][3]);
      }
      const u32 mv = umin32(umin32(m0, m1), umin32(m2, m3));
      if (__all((mv >> 16) == (u32)t)) break;      // all tags fresh
      __builtin_amdgcn_s_sleep(1);
      #pragma unroll
      for (int q = 0; q < 8; ++q) {                // re-issue stale loads
        hf[2 * q]     = load16_ag(hp + (2 * q + w) * 32);
        hf[2 * q + 1] = load16_ag(hp + (2 * q + w) * 32 + 4);
      }
    }

    // ---- h phase: repack + 16 MFMAs, once, on validated data ----
    f32x4 aH0 = {0.f, 0.f, 0.f, 0.f};
    f32x4 aH1 = {0.f, 0.f, 0.f, 0.f};
    #pragma unroll
    for (int q = 0; q < 8; ++q) {
      const int kt = 8 + 2 * q + w;
      const u32 w0 = __builtin_amdgcn_perm((u32)hf[2*q][1],   (u32)hf[2*q][0],   0x05040100u);
      const u32 w1 = __builtin_amdgcn_perm((u32)hf[2*q][3],   (u32)hf[2*q][2],   0x05040100u);
      const u32 w2 = __builtin_amdgcn_perm((u32)hf[2*q+1][1], (u32)hf[2*q+1][0], 0x05040100u);
      const u32 w3 = __builtin_amdgcn_perm((u32)hf[2*q+1][3], (u32)hf[2*q+1][2], 0x05040100u);
      const int4v ai = {(int)w0, (int)w1, (int)w2, (int)w3};
      const bf16x8 a = __builtin_bit_cast(bf16x8, ai);
      const bf16x8 b0 = *(const bf16x8*)(wf + ((0 * 24 + kt) * 64 + l) * 8);
      const bf16x8 b1 = *(const bf16x8*)(wf + ((1 * 24 + kt) * 64 + l) * 8);
      aH0 = __builtin_amdgcn_mfma_f32_16x16x32_bf16(a, b0, aH0, 0, 0, 0);
      aH1 = __builtin_amdgcn_mfma_f32_16x16x32_bf16(a, b1, aH1, 0, 0, 0);
    }

    const f32x4 z0 = aX0 + aH0;
    const f32x4 z1 = aX1 + aH1;

    // ---- cross-wave z reduce through zbuf ----
    __syncthreads();                             // WAR vs previous combine
    {
      float* zb = zbuf + ((w * 2 + 0) * 16 + (l >> 4) * 4) * 17 + (l & 15);
      #pragma unroll
      for (int r = 0; r < 4; ++r) {
        zb[r * 17]           = z0[r];
        zb[r * 17 + 16 * 17] = z1[r];            // nt=1 plane
      }
    }
    __syncthreads();

    // ---- gate math (fp32), cell update; h store FIRST (critical path) ----
    float z[4];
    #pragma unroll
    for (int gg = 0; gg < 4; ++gg) {
      const int n  = gg * 8 + uu;
      const int nt = n >> 4, nc = n & 15;
      z[gg] = zbuf[((0 + nt) * 16 + row_c) * 17 + nc]
            + zbuf[((2 + nt) * 16 + row_c) * 17 + nc]
            + breg[gg];
    }
    const float ig = sigf(z[0]);
    const float fg = sigf(z[1]);
    const float og = sigf(z[3]);
    const float cc = fg * creg + ig * z[2];
    creg = cc;
    const float hh = og * cc;
    const u32 hw = ((u32)(t + 1) << 16) | (u32)f2bf(hh);
    store4_ag(hbuf + ((size_t)((t + 1) & 1) * 64 + b_out) * Uu + u_out, hw);
    out[((size_t)b_out * Tt + t) * Uu + u_out] = tanh_fast(hh);
  }
}

extern "C" void kernel_launch(void* const* d_in, const int* in_sizes, int n_in,
                              void* d_out, int out_size, void* d_ws, size_t ws_size,
                              hipStream_t stream) {
  const float* x    = (const float*)d_in[0];
  const float* Wk   = (const float*)d_in[1];
  const float* Rk   = (const float*)d_in[2];
  const float* bias = (const float*)d_in[3];
  float* out = (float*)d_out;
  u32* hbuf = (u32*)d_ws;

  // zeroed hbuf == valid tag-0 h_0 = 0 for both parities.
  hipMemsetAsync(d_ws, 0, (size_t)2 * 64 * Uu * sizeof(u32), stream);

  (void)hipFuncSetAttribute((const void*)lstm_persistent,
                            hipFuncAttributeMaxDynamicSharedMemorySize,
                            SMEM_BYTES);

  hipLaunchKernelGGL(lstm_persistent, dim3(NWG), dim3(NTHR), SMEM_BYTES, stream,
                     x, Wk, Rk, bias, out, hbuf);
}